// Round 1
// baseline (618.249 us; speedup 1.0000x reference)
//
#include <hip/hip_runtime.h>
#include <math.h>

// Problem constants: x (B,T,C) fp32
constexpr int Bn = 16;
constexpr int Tn = 8192;
constexpr int Cn = 512;

constexpr float ALPHA    = 0.99f;
constexpr float ONE_M    = 0.01f;     // 1 - ALPHA
constexpr float EPS      = 1e-6f;
constexpr float EMA_INIT = 1e-4f;

// Sub-chunk config: one WAVE owns all C=512 channels (8 per lane) for SC timesteps.
constexpr int SC = 16;                // timesteps per sub-chunk
constexpr int NS = Tn / SC;           // 512 sub-chunks per batch row

constexpr double cpow(double a, int n) { double r = 1.0; for (int i = 0; i < n; i++) r *= a; return r; }
constexpr float ALPHA_SC = (float)cpow(0.99, SC);                // alpha^SC
constexpr float LN_ALPHA = -0.010050335853501441f;               // ln(0.99)

#if __has_builtin(__builtin_amdgcn_rcpf)
__device__ inline float fast_rcp(float x) { return __builtin_amdgcn_rcpf(x); }
#else
__device__ inline float fast_rcp(float x) { return 1.0f / x; }
#endif

typedef float f4 __attribute__((ext_vector_type(4)));

__device__ inline f4 ld4(const float* p)  { return *(const f4*)p; }
__device__ inline f4 ldnt4(const float* p){ return __builtin_nontemporal_load((const f4*)p); }
__device__ inline void stnt4(float* p, f4 v) { __builtin_nontemporal_store(v, (f4*)p); }

// ---------------- Pass 1: per-sub-chunk local carry (zero incoming state) -----
// One wave per (b, s). Lane owns channels c0..c0+7 (two dwordx4 per row).
__global__ __launch_bounds__(256) void pass1_local(const float* __restrict__ x,
                                                   float* __restrict__ carry) {
    const int gw   = blockIdx.x * 4 + (threadIdx.x >> 6);  // wave id over B*NS
    const int lane = threadIdx.x & 63;
    const int b    = gw >> 9;             // NS == 512
    const int s    = gw & (NS - 1);
    const int c0   = lane * 8;

    const float* xp = x + (size_t)(b * Tn + s * SC) * Cn + c0;

    float acc[8];
#pragma unroll
    for (int k = 0; k < 8; k++) acc[k] = 0.0f;

#pragma unroll
    for (int i = 0; i < SC; i++) {
        float v[8];
        *(f4*)&v[0] = ld4(xp + (size_t)i * Cn);
        *(f4*)&v[4] = ld4(xp + (size_t)i * Cn + 4);
#pragma unroll
        for (int k = 0; k < 8; k++)
            acc[k] = fmaf(ALPHA, acc[k], (ONE_M * v[k]) * v[k]);   // 8 independent chains
    }

    float* cp = carry + (size_t)(b * NS + s) * Cn + c0;
    *(f4*)cp       = *(f4*)&acc[0];
    *(f4*)(cp + 4) = *(f4*)&acc[4];
}

// ---------------- Pass 2: scan sub-chunk carries -> incoming state per chunk --
// 8192 independent (b,c) chains of length NS=512. Loads pipelined via unroll.
__global__ __launch_bounds__(64) void pass2_scan(const float* __restrict__ carry,
                                                 float* __restrict__ state) {
    const int idx = blockIdx.x * 64 + threadIdx.x;   // over B*Cn
    const int b = idx >> 9;                          // Cn == 512
    const int c = idx & (Cn - 1);

    const size_t base = (size_t)b * NS * Cn + c;
    float s = EMA_INIT;
#pragma unroll 8
    for (int j = 0; j < NS; j++) {
        state[base + (size_t)j * Cn] = s;                        // incoming state of sub-chunk j
        s = fmaf(ALPHA_SC, s, carry[base + (size_t)j * Cn]);     // propagate across sub-chunk
    }
}

// ---------------- Pass 3: resume scan, normalize, write y ---------------------
// One wave per (b, s): barrier-free, LDS-free. Mean over C is a single
// intra-wave butterfly (lane holds 8 contiguous channels).
__global__ __launch_bounds__(256) void pass3_norm(const float* __restrict__ x,
                                                  const float* __restrict__ state,
                                                  const float* __restrict__ gamma,
                                                  const float* __restrict__ beta,
                                                  float* __restrict__ y) {
    const int gw   = blockIdx.x * 4 + (threadIdx.x >> 6);
    const int lane = threadIdx.x & 63;
    const int b    = gw >> 9;
    const int s    = gw & (NS - 1);
    const int c0   = lane * 8;

    float ema[8], gm[8], bt[8];
    {
        const float* sp = state + (size_t)(b * NS + s) * Cn + c0;
        *(f4*)&ema[0] = ld4(sp);
        *(f4*)&ema[4] = ld4(sp + 4);
        *(f4*)&gm[0]  = ld4(gamma + c0);
        *(f4*)&gm[4]  = ld4(gamma + c0 + 4);
        *(f4*)&bt[0]  = ld4(beta + c0);
        *(f4*)&bt[4]  = ld4(beta + c0 + 4);
    }

    const int t0 = s * SC;                           // 0-based global timestep
    float p = __expf((float)t0 * LN_ALPHA);          // alpha^t0

    const float* xp = x + (size_t)(b * Tn + t0) * Cn + c0;
    float*       yp = y + (size_t)(b * Tn + t0) * Cn + c0;

    f4 xa = ldnt4(xp);
    f4 xb = ldnt4(xp + 4);

#pragma unroll
    for (int i = 0; i < SC; i++) {
        f4 na = xa, nb = xb;
        if (i + 1 < SC) {                            // prefetch next row under compute
            na = ldnt4(xp + (size_t)(i + 1) * Cn);
            nb = ldnt4(xp + (size_t)(i + 1) * Cn + 4);
        }

        p *= ALPHA;                                  // alpha^(t0+i+1)
        const float rd = fast_rcp((1.0f - p) + EPS); // 1/(denom + EPS), lane-uniform

        float g[8];
        float ls = 0.0f;
#pragma unroll
        for (int k = 0; k < 8; k++) {
            const float v = (k < 4) ? xa[k] : xb[k - 4];
            ema[k] = fmaf(ALPHA, ema[k], (ONE_M * v) * v);
            g[k]   = sqrtf(fmaf(ema[k], rd, EPS));
            ls    += g[k];
        }

        // wave-wide sum of g over all 512 channels: 6-step butterfly, no LDS
        float r = ls;
#pragma unroll
        for (int off = 32; off; off >>= 1) r += __shfl_xor(r, off, 64);
        const float invm = fast_rcp(r * (1.0f / (float)Cn) + EPS);

        f4 oa, ob;
#pragma unroll
        for (int k = 0; k < 8; k++) {
            const float v   = (k < 4) ? xa[k] : xb[k - 4];
            const float out = fmaf(gm[k], v * (g[k] * invm), bt[k] + v);
            if (k < 4) oa[k] = out; else ob[k - 4] = out;
        }
        stnt4(yp + (size_t)i * Cn, oa);
        stnt4(yp + (size_t)i * Cn + 4, ob);

        xa = na; xb = nb;
    }
}

extern "C" void kernel_launch(void* const* d_in, const int* in_sizes, int n_in,
                              void* d_out, int out_size, void* d_ws, size_t ws_size,
                              hipStream_t stream) {
    const float* x     = (const float*)d_in[0];
    const float* gamma = (const float*)d_in[1];
    const float* beta  = (const float*)d_in[2];
    float* y = (float*)d_out;

    // workspace: carries then states, each B*NS*C floats (16.78 MB each)
    float* carry = (float*)d_ws;
    float* state = carry + (size_t)Bn * NS * Cn;

    pass1_local<<<(Bn * NS) / 4, 256, 0, stream>>>(x, carry);
    pass2_scan<<<(Bn * Cn) / 64, 64, 0, stream>>>(carry, state);
    pass3_norm<<<(Bn * NS) / 4, 256, 0, stream>>>(x, state, gamma, beta, y);
}

// Round 2
// 531.261 us; speedup vs baseline: 1.1637x; 1.1637x over previous
//
#include <hip/hip_runtime.h>
#include <math.h>

// Problem constants: x (B,T,C) fp32
constexpr int Bn = 16;
constexpr int Tn = 8192;
constexpr int Cn = 512;

constexpr float ALPHA    = 0.99f;
constexpr float ONE_M    = 0.01f;     // 1 - ALPHA
constexpr float EPS      = 1e-6f;
constexpr float EMA_INIT = 1e-4f;

// Sub-chunk config: one WAVE owns all C=512 channels (8 per lane) for SC timesteps.
constexpr int SC = 16;                // timesteps per sub-chunk
constexpr int NS = Tn / SC;           // 512 sub-chunks per batch row

constexpr double cpow(double a, int n) { double r = 1.0; for (int i = 0; i < n; i++) r *= a; return r; }
constexpr float ALPHA_SC = (float)cpow(0.99, SC);                // alpha^SC
constexpr float LN_ALPHA = -0.010050335853501441f;               // ln(0.99)

#if __has_builtin(__builtin_amdgcn_rcpf)
__device__ inline float fast_rcp(float x) { return __builtin_amdgcn_rcpf(x); }
#else
__device__ inline float fast_rcp(float x) { return 1.0f / x; }
#endif

typedef float f4 __attribute__((ext_vector_type(4)));

__device__ inline f4 ld4(const float* p)  { return *(const f4*)p; }
__device__ inline f4 ldnt4(const float* p){ return __builtin_nontemporal_load((const f4*)p); }
__device__ inline void stnt4(float* p, f4 v) { __builtin_nontemporal_store(v, (f4*)p); }

// Lane->channel map: lane owns [lane*4, lane*4+4) and [256+lane*4, 256+lane*4+4).
// Every dwordx4 instruction is then 64 lanes x 16B CONTIGUOUS (1KB, full lines):
// no partial-line RMW on nontemporal stores, single-segment coalesced loads.

// ---------------- Pass 1: per-sub-chunk local carry (zero incoming state) -----
__global__ __launch_bounds__(256) void pass1_local(const float* __restrict__ x,
                                                   float* __restrict__ carry) {
    const int gw   = blockIdx.x * 4 + (threadIdx.x >> 6);  // wave id over B*NS
    const int lane = threadIdx.x & 63;
    const int b    = gw >> 9;             // NS == 512
    const int s    = gw & (NS - 1);
    const int cA   = lane * 4;            // low-half channels
    const int cB   = 256 + lane * 4;      // high-half channels

    const float* xp = x + (size_t)(b * Tn + s * SC) * Cn;

    float acc[8];
#pragma unroll
    for (int k = 0; k < 8; k++) acc[k] = 0.0f;

#pragma unroll
    for (int i = 0; i < SC; i++) {
        const f4 va = ld4(xp + (size_t)i * Cn + cA);
        const f4 vb = ld4(xp + (size_t)i * Cn + cB);
#pragma unroll
        for (int k = 0; k < 4; k++) {
            acc[k]     = fmaf(ALPHA, acc[k],     (ONE_M * va[k]) * va[k]);
            acc[k + 4] = fmaf(ALPHA, acc[k + 4], (ONE_M * vb[k]) * vb[k]);
        }
    }

    float* cp = carry + (size_t)(b * NS + s) * Cn;
    stnt4(cp + cA, *(f4*)&acc[0]);
    stnt4(cp + cB, *(f4*)&acc[4]);
}

// ---------------- Pass 2: scan sub-chunk carries -> incoming state per chunk --
// 8192 independent (b,c) chains of length NS=512. Loads pipelined via unroll.
__global__ __launch_bounds__(64) void pass2_scan(const float* __restrict__ carry,
                                                 float* __restrict__ state) {
    const int idx = blockIdx.x * 64 + threadIdx.x;   // over B*Cn
    const int b = idx >> 9;                          // Cn == 512
    const int c = idx & (Cn - 1);

    const size_t base = (size_t)b * NS * Cn + c;
    float s = EMA_INIT;
#pragma unroll 8
    for (int j = 0; j < NS; j++) {
        state[base + (size_t)j * Cn] = s;                        // incoming state of sub-chunk j
        s = fmaf(ALPHA_SC, s, carry[base + (size_t)j * Cn]);     // propagate across sub-chunk
    }
}

// ---------------- Pass 3: resume scan, normalize, write y ---------------------
// One wave per (b, s): barrier-free, LDS-free. Mean over C is a single
// intra-wave butterfly (wave covers all 512 channels).
__global__ __launch_bounds__(256) void pass3_norm(const float* __restrict__ x,
                                                  const float* __restrict__ state,
                                                  const float* __restrict__ gamma,
                                                  const float* __restrict__ beta,
                                                  float* __restrict__ y) {
    const int gw   = blockIdx.x * 4 + (threadIdx.x >> 6);
    const int lane = threadIdx.x & 63;
    const int b    = gw >> 9;
    const int s    = gw & (NS - 1);
    const int cA   = lane * 4;
    const int cB   = 256 + lane * 4;

    float ema[8], gm[8], bt[8];
    {
        const float* sp = state + (size_t)(b * NS + s) * Cn;
        *(f4*)&ema[0] = ld4(sp + cA);
        *(f4*)&ema[4] = ld4(sp + cB);
        *(f4*)&gm[0]  = ld4(gamma + cA);
        *(f4*)&gm[4]  = ld4(gamma + cB);
        *(f4*)&bt[0]  = ld4(beta + cA);
        *(f4*)&bt[4]  = ld4(beta + cB);
    }

    const int t0 = s * SC;                           // 0-based global timestep
    float p = __expf((float)t0 * LN_ALPHA);          // alpha^t0

    const float* xp = x + (size_t)(b * Tn + t0) * Cn;
    float*       yp = y + (size_t)(b * Tn + t0) * Cn;

    // 2-deep rolling prefetch (all indices compile-time after unroll)
    f4 bufA[2], bufB[2];
    bufA[0] = ldnt4(xp + cA);
    bufB[0] = ldnt4(xp + cB);
    bufA[1] = ldnt4(xp + (size_t)Cn + cA);
    bufB[1] = ldnt4(xp + (size_t)Cn + cB);

#pragma unroll
    for (int i = 0; i < SC; i++) {
        const f4 xa = bufA[i & 1];
        const f4 xb = bufB[i & 1];
        if (i + 2 < SC) {
            bufA[i & 1] = ldnt4(xp + (size_t)(i + 2) * Cn + cA);
            bufB[i & 1] = ldnt4(xp + (size_t)(i + 2) * Cn + cB);
        }

        p *= ALPHA;                                  // alpha^(t0+i+1)
        const float rd = fast_rcp((1.0f - p) + EPS); // 1/(denom + EPS), lane-uniform

        float g[8];
        float ls = 0.0f;
#pragma unroll
        for (int k = 0; k < 8; k++) {
            const float v = (k < 4) ? xa[k] : xb[k - 4];
            ema[k] = fmaf(ALPHA, ema[k], (ONE_M * v) * v);
            g[k]   = sqrtf(fmaf(ema[k], rd, EPS));
            ls    += g[k];
        }

        // wave-wide sum of g over all 512 channels: 6-step butterfly, no LDS
        float r = ls;
#pragma unroll
        for (int off = 32; off; off >>= 1) r += __shfl_xor(r, off, 64);
        const float invm = fast_rcp(r * (1.0f / (float)Cn) + EPS);

        f4 oa, ob;
#pragma unroll
        for (int k = 0; k < 8; k++) {
            const float v   = (k < 4) ? xa[k] : xb[k - 4];
            const float out = fmaf(gm[k], v * (g[k] * invm), bt[k] + v);
            if (k < 4) oa[k] = out; else ob[k - 4] = out;
        }
        stnt4(yp + (size_t)i * Cn + cA, oa);
        stnt4(yp + (size_t)i * Cn + cB, ob);
    }
}

extern "C" void kernel_launch(void* const* d_in, const int* in_sizes, int n_in,
                              void* d_out, int out_size, void* d_ws, size_t ws_size,
                              hipStream_t stream) {
    const float* x     = (const float*)d_in[0];
    const float* gamma = (const float*)d_in[1];
    const float* beta  = (const float*)d_in[2];
    float* y = (float*)d_out;

    // workspace: carries then states, each B*NS*C floats (16.78 MB each)
    float* carry = (float*)d_ws;
    float* state = carry + (size_t)Bn * NS * Cn;

    pass1_local<<<(Bn * NS) / 4, 256, 0, stream>>>(x, carry);
    pass2_scan<<<(Bn * Cn) / 64, 64, 0, stream>>>(carry, state);
    pass3_norm<<<(Bn * NS) / 4, 256, 0, stream>>>(x, state, gamma, beta, y);
}

// Round 3
// 494.231 us; speedup vs baseline: 1.2509x; 1.0749x over previous
//
#include <hip/hip_runtime.h>
#include <math.h>

// Problem constants: x (B,T,C) fp32
constexpr int Bn = 16;
constexpr int Tn = 8192;
constexpr int Cn = 512;

constexpr float ALPHA    = 0.99f;
constexpr float ONE_M    = 0.01f;     // 1 - ALPHA
constexpr float EPS      = 1e-6f;
constexpr float EMA_INIT = 1e-4f;

// Sub-chunk config: one WAVE owns all C=512 channels (8 per lane) for SC timesteps.
constexpr int SC = 16;                // timesteps per sub-chunk
constexpr int NS = Tn / SC;           // 512 sub-chunks per batch row

// pass2 decay-split: 4 independent segments of 128 chunks, 64-chunk warmup.
// alpha^(64*16) = alpha^1024 ~= 3.4e-5 -> truncation error far below tolerance.
constexpr int SEGLEN = 128;
constexpr int NSEG   = NS / SEGLEN;   // 4
constexpr int WARM   = 64;

constexpr double cpow(double a, int n) { double r = 1.0; for (int i = 0; i < n; i++) r *= a; return r; }
constexpr float ALPHA_SC = (float)cpow(0.99, SC);                // alpha^SC
constexpr float LN_ALPHA = -0.010050335853501441f;               // ln(0.99)

#if __has_builtin(__builtin_amdgcn_rcpf)
__device__ inline float fast_rcp(float x) { return __builtin_amdgcn_rcpf(x); }
#else
__device__ inline float fast_rcp(float x) { return 1.0f / x; }
#endif

typedef float f4 __attribute__((ext_vector_type(4)));

__device__ inline f4 ld4(const float* p)  { return *(const f4*)p; }
__device__ inline f4 ldnt4(const float* p){ return __builtin_nontemporal_load((const f4*)p); }
__device__ inline void stnt4(float* p, f4 v) { __builtin_nontemporal_store(v, (f4*)p); }
__device__ inline void st4(float* p, f4 v)   { *(f4*)p = v; }

// Lane->channel map: lane owns [lane*4, lane*4+4) and [256+lane*4, 256+lane*4+4).
// Every dwordx4 instruction is 64 lanes x 16B CONTIGUOUS (1KB, full lines).

// ---------------- Pass 1: per-sub-chunk local carry (zero incoming state) -----
__global__ __launch_bounds__(256) void pass1_local(const float* __restrict__ x,
                                                   float* __restrict__ carry) {
    const int gw   = blockIdx.x * 4 + (threadIdx.x >> 6);  // wave id over B*NS
    const int lane = threadIdx.x & 63;
    const int b    = gw >> 9;             // NS == 512
    const int s    = gw & (NS - 1);
    const int cA   = lane * 4;            // low-half channels
    const int cB   = 256 + lane * 4;      // high-half channels

    const float* xp = x + (size_t)(b * Tn + s * SC) * Cn;

    float acc[8];
#pragma unroll
    for (int k = 0; k < 8; k++) acc[k] = 0.0f;

#pragma unroll
    for (int i = 0; i < SC; i++) {
        const f4 va = ld4(xp + (size_t)i * Cn + cA);
        const f4 vb = ld4(xp + (size_t)i * Cn + cB);
#pragma unroll
        for (int k = 0; k < 4; k++) {
            acc[k]     = fmaf(ALPHA, acc[k],     (ONE_M * va[k]) * va[k]);
            acc[k + 4] = fmaf(ALPHA, acc[k + 4], (ONE_M * vb[k]) * vb[k]);
        }
    }

    // cached stores: carry is consumed by pass2 shortly -> keep in L2/L3
    float* cp = carry + (size_t)(b * NS + s) * Cn;
    st4(cp + cA, *(f4*)&acc[0]);
    st4(cp + cB, *(f4*)&acc[4]);
}

// ---------------- Pass 2: scan sub-chunk carries -> incoming state per chunk --
// Decay-split: thread = (b, seg, c). Each scans WARM warmup chunks (from zero;
// alpha^1024 truncation) then SEGLEN real chunks. 32768 threads, 192 iters.
__global__ __launch_bounds__(256) void pass2_scan(const float* __restrict__ carry,
                                                  float* __restrict__ state) {
    const int idx = blockIdx.x * 256 + threadIdx.x;  // over Bn*NSEG*Cn = 32768
    const int c   = idx & (Cn - 1);
    const int seg = (idx >> 9) & (NSEG - 1);
    const int b   = idx >> 11;

    const size_t base = (size_t)b * NS * Cn + c;
    const int j0 = seg * SEGLEN;

    float s;
    if (seg == 0) {
        s = EMA_INIT;
    } else {
        s = 0.0f;
#pragma unroll 8
        for (int j = j0 - WARM; j < j0; j++)
            s = fmaf(ALPHA_SC, s, carry[base + (size_t)j * Cn]);
    }
#pragma unroll 8
    for (int j = j0; j < j0 + SEGLEN; j++) {
        state[base + (size_t)j * Cn] = s;                        // incoming state of chunk j
        s = fmaf(ALPHA_SC, s, carry[base + (size_t)j * Cn]);     // propagate across chunk
    }
}

// ---------------- Pass 3: resume scan, normalize, write y ---------------------
// One wave per (b, s): barrier-free, LDS-free. Mean over C is a single
// intra-wave butterfly (wave covers all 512 channels).
__global__ __launch_bounds__(256) void pass3_norm(const float* __restrict__ x,
                                                  const float* __restrict__ state,
                                                  const float* __restrict__ gamma,
                                                  const float* __restrict__ beta,
                                                  float* __restrict__ y) {
    const int gw   = blockIdx.x * 4 + (threadIdx.x >> 6);
    const int lane = threadIdx.x & 63;
    const int b    = gw >> 9;
    const int s    = gw & (NS - 1);
    const int cA   = lane * 4;
    const int cB   = 256 + lane * 4;

    float ema[8], gm[8], bt[8];
    {
        const float* sp = state + (size_t)(b * NS + s) * Cn;
        *(f4*)&ema[0] = ld4(sp + cA);
        *(f4*)&ema[4] = ld4(sp + cB);
        *(f4*)&gm[0]  = ld4(gamma + cA);
        *(f4*)&gm[4]  = ld4(gamma + cB);
        *(f4*)&bt[0]  = ld4(beta + cA);
        *(f4*)&bt[4]  = ld4(beta + cB);
    }

    const int t0 = s * SC;                           // 0-based global timestep
    float p = __expf((float)t0 * LN_ALPHA);          // alpha^t0

    const float* xp = x + (size_t)(b * Tn + t0) * Cn;
    float*       yp = y + (size_t)(b * Tn + t0) * Cn;

    // 2-deep rolling prefetch (all indices compile-time after unroll)
    f4 bufA[2], bufB[2];
    bufA[0] = ldnt4(xp + cA);
    bufB[0] = ldnt4(xp + cB);
    bufA[1] = ldnt4(xp + (size_t)Cn + cA);
    bufB[1] = ldnt4(xp + (size_t)Cn + cB);

#pragma unroll
    for (int i = 0; i < SC; i++) {
        const f4 xa = bufA[i & 1];
        const f4 xb = bufB[i & 1];
        if (i + 2 < SC) {
            bufA[i & 1] = ldnt4(xp + (size_t)(i + 2) * Cn + cA);
            bufB[i & 1] = ldnt4(xp + (size_t)(i + 2) * Cn + cB);
        }

        p *= ALPHA;                                  // alpha^(t0+i+1)
        const float rd = fast_rcp((1.0f - p) + EPS); // 1/(denom + EPS), lane-uniform

        float g[8];
        float ls = 0.0f;
#pragma unroll
        for (int k = 0; k < 8; k++) {
            const float v = (k < 4) ? xa[k] : xb[k - 4];
            ema[k] = fmaf(ALPHA, ema[k], (ONE_M * v) * v);
            g[k]   = sqrtf(fmaf(ema[k], rd, EPS));
            ls    += g[k];
        }

        // wave-wide sum of g over all 512 channels: 6-step butterfly, no LDS
        float r = ls;
#pragma unroll
        for (int off = 32; off; off >>= 1) r += __shfl_xor(r, off, 64);
        const float invm = fast_rcp(r * (1.0f / (float)Cn) + EPS);

        f4 oa, ob;
#pragma unroll
        for (int k = 0; k < 8; k++) {
            const float v   = (k < 4) ? xa[k] : xb[k - 4];
            const float out = fmaf(gm[k], v * (g[k] * invm), bt[k] + v);
            if (k < 4) oa[k] = out; else ob[k - 4] = out;
        }
        stnt4(yp + (size_t)i * Cn + cA, oa);
        stnt4(yp + (size_t)i * Cn + cB, ob);
    }
}

extern "C" void kernel_launch(void* const* d_in, const int* in_sizes, int n_in,
                              void* d_out, int out_size, void* d_ws, size_t ws_size,
                              hipStream_t stream) {
    const float* x     = (const float*)d_in[0];
    const float* gamma = (const float*)d_in[1];
    const float* beta  = (const float*)d_in[2];
    float* y = (float*)d_out;

    // workspace: carries then states, each B*NS*C floats (16.78 MB each)
    float* carry = (float*)d_ws;
    float* state = carry + (size_t)Bn * NS * Cn;

    pass1_local<<<(Bn * NS) / 4, 256, 0, stream>>>(x, carry);
    pass2_scan<<<(Bn * NSEG * Cn) / 256, 256, 0, stream>>>(carry, state);
    pass3_norm<<<(Bn * NS) / 4, 256, 0, stream>>>(x, state, gamma, beta, y);
}